// Round 1
// baseline (511.193 us; speedup 1.0000x reference)
//
#include <hip/hip_runtime.h>

// Problem constants (fixed by the reference)
#define BB 4
#define NS 4096
#define NT 4096
#define FS 256
#define FT 256
#define FO 64
#define ALPHA 0.2f
#define OUT_SLOPE 0.01f
#define L2E 1.4426950408889634f  // log2(e): score vectors pre-scaled so k_part uses exp2

typedef __attribute__((ext_vector_type(8))) short short8;
typedef __attribute__((ext_vector_type(4))) float floatx4;

__device__ __forceinline__ float leaky(float x, float s) { return x > 0.f ? x : s * x; }
// leaky with slope<1 == max(x, slope*x)
__device__ __forceinline__ float leaky_max(float x, float s) { return fmaxf(x, s * x); }

// fp32 -> bf16 with round-to-nearest-even (scalar path, used in k_wsctx)
__device__ __forceinline__ short f2bf(float x) {
  union { float f; unsigned u; } c; c.f = x;
  unsigned r = c.u + 0x7fffu + ((c.u >> 16) & 1u);
  return (short)(r >> 16);
}

// packed fp32x2 -> bf16x2 in one instruction (gfx950; lo -> bits[15:0])
__device__ __forceinline__ unsigned cvt_pk_bf16(float lo, float hi) {
  unsigned r;
  asm("v_cvt_pk_bf16_f32 %0, %1, %2" : "=v"(r) : "v"(lo), "v"(hi));
  return r;
}

// wa[f] = L2E * sum_o Wt[f, o] * a[FO + o]   (256-vector, pre-scaled by log2e)
__global__ void k_wa(const float* __restrict__ Wt, const float* __restrict__ a,
                     float* __restrict__ wa) {
  int f = threadIdx.x;  // 0..255
  float acc = 0.f;
#pragma unroll
  for (int o = 0; o < FO; ++o) acc += Wt[f * FO + o] * a[FO + o];
  wa[f] = acc * L2E;
}

// t[row] = dot(h[row, :256], wa)   one wave per row (already log2e-scaled via wa)
__global__ __launch_bounds__(256) void k_t(const float* __restrict__ h,
                                           const float* __restrict__ wa,
                                           float* __restrict__ tvec) {
  int lane = threadIdx.x & 63, wave = threadIdx.x >> 6;
  int row = blockIdx.x * 4 + wave;  // 0..B*NT-1
  const float4* hp = (const float4*)(h + (size_t)row * FT);
  const float4* wp = (const float4*)wa;
  float4 hv = hp[lane], wv = wp[lane];
  float acc = hv.x * wv.x + hv.y * wv.y + hv.z * wv.z + hv.w * wv.w;
#pragma unroll
  for (int off = 32; off; off >>= 1) acc += __shfl_down(acc, off);
  if (lane == 0) tvec[row] = acc;
}

// per-batch max of t (softmax shift; any per-row-valid upper bound works)
__global__ __launch_bounds__(256) void k_tmax(const float* __restrict__ tvec,
                                              float* __restrict__ tmax) {
  __shared__ float red[256];
  int b = blockIdx.x, tid = threadIdx.x;
  float m = -3.0e38f;
  for (int j = tid; j < NS; j += 256) m = fmaxf(m, tvec[b * NS + j]);
  red[tid] = m;
  __syncthreads();
  for (int s = 128; s; s >>= 1) {
    if (tid < s) red[tid] = fmaxf(red[tid], red[tid + s]);
    __syncthreads();
  }
  if (tid == 0) tmax[b] = red[0];
}

// Ws_ctx = ctx @ Ws; writes TRANSPOSED bf16 vT[b][f][row] (MFMA B-operand feed)
// and s[row] = L2E * (Ws_ctx[row,:] @ a[:64]).  One wave per 4 rows, 64 lanes = f.
__global__ __launch_bounds__(256) void k_wsctx(const float* __restrict__ ctx,
                                               const float* __restrict__ Ws,
                                               const float* __restrict__ a,
                                               short* __restrict__ vT,
                                               float* __restrict__ svec) {
  const int f = threadIdx.x & 63, wave = threadIdx.x >> 6;
  const int row0 = blockIdx.x * 16 + wave * 4;  // global row in [0, B*NS)
  const float4* c0 = (const float4*)(ctx + (size_t)(row0 + 0) * FS);
  const float4* c1 = (const float4*)(ctx + (size_t)(row0 + 1) * FS);
  const float4* c2 = (const float4*)(ctx + (size_t)(row0 + 2) * FS);
  const float4* c3 = (const float4*)(ctx + (size_t)(row0 + 3) * FS);
  float r0 = 0.f, r1 = 0.f, r2 = 0.f, r3 = 0.f;
#pragma unroll 2
  for (int k4 = 0; k4 < FS / 4; ++k4) {
    const float w0 = Ws[(k4 * 4 + 0) * FO + f];
    const float w1 = Ws[(k4 * 4 + 1) * FO + f];
    const float w2 = Ws[(k4 * 4 + 2) * FO + f];
    const float w3 = Ws[(k4 * 4 + 3) * FO + f];
    float4 x;
    x = c0[k4]; r0 += x.x * w0 + x.y * w1 + x.z * w2 + x.w * w3;
    x = c1[k4]; r1 += x.x * w0 + x.y * w1 + x.z * w2 + x.w * w3;
    x = c2[k4]; r2 += x.x * w0 + x.y * w1 + x.z * w2 + x.w * w3;
    x = c3[k4]; r3 += x.x * w0 + x.y * w1 + x.z * w2 + x.w * w3;
  }
  const int b = row0 >> 12;             // NS = 4096 rows per batch
  const int rloc = row0 & (NS - 1);
  short* vp = vT + ((size_t)b * FO + f) * NS + rloc;
  vp[0] = f2bf(r0); vp[1] = f2bf(r1); vp[2] = f2bf(r2); vp[3] = f2bf(r3);

  const float af = a[f] * L2E;          // fold log2e into the score vector
  float s0 = r0 * af, s1 = r1 * af, s2 = r2 * af, s3 = r3 * af;
#pragma unroll
  for (int off = 32; off; off >>= 1) {
    s0 += __shfl_down(s0, off);
    s1 += __shfl_down(s1, off);
    s2 += __shfl_down(s2, off);
    s3 += __shfl_down(s3, off);
  }
  if (f == 0) {
    svec[row0 + 0] = s0;
    svec[row0 + 1] = s1;
    svec[row0 + 2] = s2;
    svec[row0 + 3] = s3;
  }
}

// MFMA partial attention: each wave owns 16 rows, computes w on the fly
// (A-frag = 8 consecutive j per lane, generated in-register; no LDS),
// B-frag = 16B contiguous load from vT.  Partials per j-split, no atomics.
// Score vectors are pre-scaled by log2e so w = exp2(leaky(s+t) - cr).
template <int JS>
__global__ __launch_bounds__(256) void k_part(const int* __restrict__ adj,
                                              const short* __restrict__ vT,
                                              const float* __restrict__ svec,
                                              const float* __restrict__ tvec,
                                              const float* __restrict__ tmax,
                                              float* __restrict__ outpart,
                                              float* __restrict__ lpart) {
  const int lane = threadIdx.x & 63;
  const int wv = threadIdx.x >> 6;   // 0..3
  const int m = lane & 15;           // A row within 16 / B,D col (f within 16)
  const int q = lane >> 4;           // quad: k-offset q*8

  constexpr int LOG = (JS == 8) ? 3 : 2;
  const int tile = blockIdx.x >> LOG;    // 256 row-tiles of 64
  const int js = blockIdx.x & (JS - 1);
  const int b = tile >> 6;               // 64 tiles per batch
  const int i0 = (tile & 63) * 64;
  const int jbase = js * (NS / JS);

  const int r = i0 + wv * 16 + m;        // this lane's target row (within batch)
  const float sr = svec[b * NS + r];
  const float cr = leaky_max(sr + tmax[b], ALPHA);

  const int* arow = adj + ((size_t)(b * NT) + r) * NS + jbase;
  const float* tp = tvec + b * NS + jbase;
  const short* vp0 = vT + ((size_t)b * FO + m) * NS + jbase;  // + ft*16*NS

  floatx4 acc0 = {0.f, 0.f, 0.f, 0.f};
  floatx4 acc1 = {0.f, 0.f, 0.f, 0.f};
  floatx4 acc2 = {0.f, 0.f, 0.f, 0.f};
  floatx4 acc3 = {0.f, 0.f, 0.f, 0.f};
  float lsum = 0.f;

#pragma unroll 2
  for (int jc = 0; jc < (NS / JS) / 32; ++jc) {
    const int j0 = jc * 32 + q * 8;
    const int4 a0 = *(const int4*)(arow + j0);
    const int4 a1 = *(const int4*)(arow + j0 + 4);
    const float4 t0 = *(const float4*)(tp + j0);
    const float4 t1 = *(const float4*)(tp + j0 + 4);

    float w[8];
    w[0] = (a0.x > 0) ? __builtin_amdgcn_exp2f(leaky_max(sr + t0.x, ALPHA) - cr) : 0.f;
    w[1] = (a0.y > 0) ? __builtin_amdgcn_exp2f(leaky_max(sr + t0.y, ALPHA) - cr) : 0.f;
    w[2] = (a0.z > 0) ? __builtin_amdgcn_exp2f(leaky_max(sr + t0.z, ALPHA) - cr) : 0.f;
    w[3] = (a0.w > 0) ? __builtin_amdgcn_exp2f(leaky_max(sr + t0.w, ALPHA) - cr) : 0.f;
    w[4] = (a1.x > 0) ? __builtin_amdgcn_exp2f(leaky_max(sr + t1.x, ALPHA) - cr) : 0.f;
    w[5] = (a1.y > 0) ? __builtin_amdgcn_exp2f(leaky_max(sr + t1.y, ALPHA) - cr) : 0.f;
    w[6] = (a1.z > 0) ? __builtin_amdgcn_exp2f(leaky_max(sr + t1.z, ALPHA) - cr) : 0.f;
    w[7] = (a1.w > 0) ? __builtin_amdgcn_exp2f(leaky_max(sr + t1.w, ALPHA) - cr) : 0.f;

    lsum += ((w[0] + w[1]) + (w[2] + w[3])) + ((w[4] + w[5]) + (w[6] + w[7]));

    union { short8 s; unsigned u[4]; } afu;
    afu.u[0] = cvt_pk_bf16(w[0], w[1]);
    afu.u[1] = cvt_pk_bf16(w[2], w[3]);
    afu.u[2] = cvt_pk_bf16(w[4], w[5]);
    afu.u[3] = cvt_pk_bf16(w[6], w[7]);
    const short8 af = afu.s;

    const short8 bf0 = *(const short8*)(vp0 + 0 * 16 * NS + j0);
    const short8 bf1 = *(const short8*)(vp0 + 1 * 16 * NS + j0);
    const short8 bf2 = *(const short8*)(vp0 + 2 * 16 * NS + j0);
    const short8 bf3 = *(const short8*)(vp0 + 3 * 16 * NS + j0);
    acc0 = __builtin_amdgcn_mfma_f32_16x16x32_bf16(af, bf0, acc0, 0, 0, 0);
    acc1 = __builtin_amdgcn_mfma_f32_16x16x32_bf16(af, bf1, acc1, 0, 0, 0);
    acc2 = __builtin_amdgcn_mfma_f32_16x16x32_bf16(af, bf2, acc2, 0, 0, 0);
    acc3 = __builtin_amdgcn_mfma_f32_16x16x32_bf16(af, bf3, acc3, 0, 0, 0);
  }

  // denominator partial: reduce lsum over the 4 quads holding the same row m
  float v = lsum;
  v += __shfl_down(v, 32);
  v += __shfl_down(v, 16);
  if (lane < 16) lpart[(size_t)js * BB * NT + (size_t)b * NT + i0 + wv * 16 + m] = v;

  // numerator partial: D layout col=lane&15, row=(lane>>4)*4+reg
  float* op = outpart + (size_t)js * BB * NT * FO +
              ((size_t)(b * NT) + i0 + wv * 16 + q * 4) * FO + m;
#pragma unroll
  for (int reg = 0; reg < 4; ++reg) {
    op[(size_t)reg * FO + 0 * 16] = acc0[reg];
    op[(size_t)reg * FO + 1 * 16] = acc1[reg];
    op[(size_t)reg * FO + 2 * 16] = acc2[reg];
    op[(size_t)reg * FO + 3 * 16] = acc3[reg];
  }
}

// out[i,f] = leaky( (sum_js outpart) / (sum_js lpart), 0.01 ), float4-vectorized
template <int JS>
__global__ __launch_bounds__(256) void k_fin(const float* __restrict__ outpart,
                                             const float* __restrict__ lpart,
                                             float* __restrict__ out) {
  const size_t NP = (size_t)BB * NT * FO;   // floats per partial
  const int idx = blockIdx.x * 256 + threadIdx.x;   // float4 index
  const int row = idx >> 4;                          // 16 float4 per row
  float l = 0.f;
#pragma unroll
  for (int s = 0; s < JS; ++s) l += lpart[(size_t)s * BB * NT + row];
  const float inv = 1.f / l;
  float4 acc = {0.f, 0.f, 0.f, 0.f};
#pragma unroll
  for (int s = 0; s < JS; ++s) {
    float4 v = ((const float4*)(outpart + (size_t)s * NP))[idx];
    acc.x += v.x; acc.y += v.y; acc.z += v.z; acc.w += v.w;
  }
  float4 o;
  o.x = leaky_max(acc.x * inv, OUT_SLOPE);
  o.y = leaky_max(acc.y * inv, OUT_SLOPE);
  o.z = leaky_max(acc.z * inv, OUT_SLOPE);
  o.w = leaky_max(acc.w * inv, OUT_SLOPE);
  ((float4*)out)[idx] = o;
}

extern "C" void kernel_launch(void* const* d_in, const int* in_sizes, int n_in,
                              void* d_out, int out_size, void* d_ws, size_t ws_size,
                              hipStream_t stream) {
  const float* h   = (const float*)d_in[0];  // [B, Nt, Ft]
  const float* ctx = (const float*)d_in[1];  // [B, Ns, Fs]
  const int*   adj = (const int*)d_in[2];    // [B, Nt, Ns]
  const float* Ws  = (const float*)d_in[3];  // [Fs, Fo]
  const float* Wt  = (const float*)d_in[4];  // [Ft, Fo]
  const float* a   = (const float*)d_in[5];  // [2*Fo, 1]
  float* out = (float*)d_out;                // [B, Nt, Fo] fp32
  float* ws = (float*)d_ws;

  // JSPLIT=8 doubles resident waves in k_part (latency hiding); falls back to
  // the previously-verified JSPLIT=4 layout if the workspace is too small.
  const size_t np = (size_t)BB * NT * FO;              // outpart floats per split
  const size_t fixed_f = 2 * (size_t)BB * NS + 256 + 4; // tvec+svec+wa+tmax
  const size_t vt_bytes = (size_t)BB * FO * NS * 2;
  const size_t need8 = ((size_t)8 * np + (size_t)8 * BB * NT + fixed_f) * sizeof(float) + vt_bytes;
  const int js = (ws_size >= need8) ? 8 : 4;

  float* outpart = ws;                                  // js * B*NT*FO
  float* lpart   = outpart + (size_t)js * np;           // js * B*NT
  float* tvec    = lpart + (size_t)js * BB * NT;        // 16384
  float* svec    = tvec + BB * NS;                      // 16384
  float* wa      = svec + BB * NS;                      // 256
  float* tmax    = wa + 256;                            // 4
  short* vT      = (short*)(tmax + 4);                  // B*FO*NS bf16 = 2 MB

  k_wa<<<1, 256, 0, stream>>>(Wt, a, wa);
  k_t<<<(BB * NT) / 4, 256, 0, stream>>>(h, wa, tvec);
  k_tmax<<<BB, 256, 0, stream>>>(tvec, tmax);
  k_wsctx<<<(BB * NS) / 16, 256, 0, stream>>>(ctx, Ws, a, vT, svec);
  if (js == 8) {
    k_part<8><<<(BB * NT / 64) * 8, 256, 0, stream>>>(adj, vT, svec, tvec, tmax,
                                                      outpart, lpart);
    k_fin<8><<<(BB * NT * FO / 4) / 256, 256, 0, stream>>>(outpart, lpart, out);
  } else {
    k_part<4><<<(BB * NT / 64) * 4, 256, 0, stream>>>(adj, vT, svec, tvec, tmax,
                                                      outpart, lpart);
    k_fin<4><<<(BB * NT * FO / 4) / 256, 256, 0, stream>>>(outpart, lpart, out);
  }
}

// Round 2
// 493.292 us; speedup vs baseline: 1.0363x; 1.0363x over previous
//
#include <hip/hip_runtime.h>

// Problem constants (fixed by the reference)
#define BB 4
#define NS 4096
#define NT 4096
#define FS 256
#define FT 256
#define FO 64
#define ALPHA 0.2f
#define OUT_SLOPE 0.01f
#define JSPLIT 4
#define L2E 1.4426950408889634f  // log2(e): score vectors pre-scaled so k_part uses exp2

typedef __attribute__((ext_vector_type(8))) short short8;
typedef __attribute__((ext_vector_type(4))) float floatx4;

__device__ __forceinline__ float leaky_max(float x, float s) { return fmaxf(x, s * x); }

// fp32 -> bf16 round-to-nearest-even (scalar path, k_wsctx)
__device__ __forceinline__ short f2bf(float x) {
  union { float f; unsigned u; } c; c.f = x;
  unsigned r = c.u + 0x7fffu + ((c.u >> 16) & 1u);
  return (short)(r >> 16);
}

// packed fp32x2 -> bf16x2 (gfx950; lo -> bits[15:0])
__device__ __forceinline__ unsigned cvt_pk_bf16(float lo, float hi) {
  unsigned r;
  asm("v_cvt_pk_bf16_f32 %0, %1, %2" : "=v"(r) : "v"(lo), "v"(hi));
  return r;
}

// wa[f] = L2E * sum_o Wt[f, o] * a[FO + o]
__global__ void k_wa(const float* __restrict__ Wt, const float* __restrict__ a,
                     float* __restrict__ wa) {
  int f = threadIdx.x;
  float acc = 0.f;
#pragma unroll
  for (int o = 0; o < FO; ++o) acc += Wt[f * FO + o] * a[FO + o];
  wa[f] = acc * L2E;
}

// t[row] = dot(h[row, :256], wa)   one wave per row (log2e-scaled via wa)
__global__ __launch_bounds__(256) void k_t(const float* __restrict__ h,
                                           const float* __restrict__ wa,
                                           float* __restrict__ tvec) {
  int lane = threadIdx.x & 63, wave = threadIdx.x >> 6;
  int row = blockIdx.x * 4 + wave;
  const float4* hp = (const float4*)(h + (size_t)row * FT);
  const float4* wp = (const float4*)wa;
  float4 hv = hp[lane], wv = wp[lane];
  float acc = hv.x * wv.x + hv.y * wv.y + hv.z * wv.z + hv.w * wv.w;
#pragma unroll
  for (int off = 32; off; off >>= 1) acc += __shfl_down(acc, off);
  if (lane == 0) tvec[row] = acc;
}

// per-batch max of t (softmax shift)
__global__ __launch_bounds__(256) void k_tmax(const float* __restrict__ tvec,
                                              float* __restrict__ tmax) {
  __shared__ float red[256];
  int b = blockIdx.x, tid = threadIdx.x;
  float m = -3.0e38f;
  for (int j = tid; j < NS; j += 256) m = fmaxf(m, tvec[b * NS + j]);
  red[tid] = m;
  __syncthreads();
  for (int s = 128; s; s >>= 1) {
    if (tid < s) red[tid] = fmaxf(red[tid], red[tid + s]);
    __syncthreads();
  }
  if (tid == 0) tmax[b] = red[0];
}

// Ws_ctx = ctx @ Ws; writes TRANSPOSED bf16 vT[b][f][row] and
// s[row] = L2E * (Ws_ctx[row,:] @ a[:64]).  One wave per 4 rows, 64 lanes = f.
__global__ __launch_bounds__(256) void k_wsctx(const float* __restrict__ ctx,
                                               const float* __restrict__ Ws,
                                               const float* __restrict__ a,
                                               short* __restrict__ vT,
                                               float* __restrict__ svec) {
  const int f = threadIdx.x & 63, wave = threadIdx.x >> 6;
  const int row0 = blockIdx.x * 16 + wave * 4;
  const float4* c0 = (const float4*)(ctx + (size_t)(row0 + 0) * FS);
  const float4* c1 = (const float4*)(ctx + (size_t)(row0 + 1) * FS);
  const float4* c2 = (const float4*)(ctx + (size_t)(row0 + 2) * FS);
  const float4* c3 = (const float4*)(ctx + (size_t)(row0 + 3) * FS);
  float r0 = 0.f, r1 = 0.f, r2 = 0.f, r3 = 0.f;
#pragma unroll 2
  for (int k4 = 0; k4 < FS / 4; ++k4) {
    const float w0 = Ws[(k4 * 4 + 0) * FO + f];
    const float w1 = Ws[(k4 * 4 + 1) * FO + f];
    const float w2 = Ws[(k4 * 4 + 2) * FO + f];
    const float w3 = Ws[(k4 * 4 + 3) * FO + f];
    float4 x;
    x = c0[k4]; r0 += x.x * w0 + x.y * w1 + x.z * w2 + x.w * w3;
    x = c1[k4]; r1 += x.x * w0 + x.y * w1 + x.z * w2 + x.w * w3;
    x = c2[k4]; r2 += x.x * w0 + x.y * w1 + x.z * w2 + x.w * w3;
    x = c3[k4]; r3 += x.x * w0 + x.y * w1 + x.z * w2 + x.w * w3;
  }
  const int b = row0 >> 12;
  const int rloc = row0 & (NS - 1);
  short* vp = vT + ((size_t)b * FO + f) * NS + rloc;
  vp[0] = f2bf(r0); vp[1] = f2bf(r1); vp[2] = f2bf(r2); vp[3] = f2bf(r3);

  const float af = a[f] * L2E;
  float s0 = r0 * af, s1 = r1 * af, s2 = r2 * af, s3 = r3 * af;
#pragma unroll
  for (int off = 32; off; off >>= 1) {
    s0 += __shfl_down(s0, off);
    s1 += __shfl_down(s1, off);
    s2 += __shfl_down(s2, off);
    s3 += __shfl_down(s3, off);
  }
  if (f == 0) {
    svec[row0 + 0] = s0;
    svec[row0 + 1] = s1;
    svec[row0 + 2] = s2;
    svec[row0 + 3] = s3;
  }
}

// MFMA partial attention, explicitly software-pipelined (depth-1 full-chunk
// double-buffer).  The previous version compiled to VGPR=40: the compiler
// recycled one load-register set per chunk, draining vmcnt inside every
// chunk -> ~1400 cy serial/chunk, all pipes <13% busy.  Here two named
// register sets alternate; chunk c+1's 8 loads are issued before chunk c's
// compute, so one full chunk (8x16B x 64 lanes) stays in flight per wave.
// __launch_bounds__(256,4) lifts the VGPR cap to 128 (~112 used).
template <int JS>
__global__ __launch_bounds__(256, 4) void k_part(const int* __restrict__ adj,
                                                 const short* __restrict__ vT,
                                                 const float* __restrict__ svec,
                                                 const float* __restrict__ tvec,
                                                 const float* __restrict__ tmax,
                                                 float* __restrict__ outpart,
                                                 float* __restrict__ lpart) {
  const int lane = threadIdx.x & 63;
  const int wv = threadIdx.x >> 6;   // 0..3
  const int m = lane & 15;           // A row within 16 / B,D col (f within 16)
  const int q = lane >> 4;           // quad: k-offset q*8

  constexpr int LOG = (JS == 8) ? 3 : 2;
  constexpr int NC = (NS / JS) / 32;     // 32-j chunks per block
  const int tile = blockIdx.x >> LOG;
  const int js = blockIdx.x & (JS - 1);
  const int b = tile >> 6;
  const int i0 = (tile & 63) * 64;
  const int jbase = js * (NS / JS);

  const int r = i0 + wv * 16 + m;
  const float sr = svec[b * NS + r];
  const float cr = leaky_max(sr + tmax[b], ALPHA);

  const int* arow = adj + ((size_t)(b * NT) + r) * NS + jbase;
  const float* tp = tvec + b * NS + jbase;
  const short* vp0 = vT + ((size_t)b * FO + m) * NS + jbase;

  floatx4 acc0 = {0.f, 0.f, 0.f, 0.f};
  floatx4 acc1 = {0.f, 0.f, 0.f, 0.f};
  floatx4 acc2 = {0.f, 0.f, 0.f, 0.f};
  floatx4 acc3 = {0.f, 0.f, 0.f, 0.f};
  float lsum = 0.f;

  // two named full-chunk register sets
  int4 Aa0, Aa1; float4 At0, At1; short8 Av0, Av1, Av2, Av3;
  int4 Ba0, Ba1; float4 Bt0, Bt1; short8 Bv0, Bv1, Bv2, Bv3;

#define ISSUE(S, jc) do {                                        \
    const int j0_ = (jc) * 32 + q * 8;                           \
    S##a0 = *(const int4*)(arow + j0_);                          \
    S##a1 = *(const int4*)(arow + j0_ + 4);                      \
    S##t0 = *(const float4*)(tp + j0_);                          \
    S##t1 = *(const float4*)(tp + j0_ + 4);                      \
    S##v0 = *(const short8*)(vp0 + 0 * 16 * NS + j0_);           \
    S##v1 = *(const short8*)(vp0 + 1 * 16 * NS + j0_);           \
    S##v2 = *(const short8*)(vp0 + 2 * 16 * NS + j0_);           \
    S##v3 = *(const short8*)(vp0 + 3 * 16 * NS + j0_);           \
  } while (0)

#define COMPUTE(S) do {                                                         \
    float w0 = (S##a0.x > 0) ? __builtin_amdgcn_exp2f(leaky_max(sr + S##t0.x, ALPHA) - cr) : 0.f; \
    float w1 = (S##a0.y > 0) ? __builtin_amdgcn_exp2f(leaky_max(sr + S##t0.y, ALPHA) - cr) : 0.f; \
    float w2 = (S##a0.z > 0) ? __builtin_amdgcn_exp2f(leaky_max(sr + S##t0.z, ALPHA) - cr) : 0.f; \
    float w3 = (S##a0.w > 0) ? __builtin_amdgcn_exp2f(leaky_max(sr + S##t0.w, ALPHA) - cr) : 0.f; \
    float w4 = (S##a1.x > 0) ? __builtin_amdgcn_exp2f(leaky_max(sr + S##t1.x, ALPHA) - cr) : 0.f; \
    float w5 = (S##a1.y > 0) ? __builtin_amdgcn_exp2f(leaky_max(sr + S##t1.y, ALPHA) - cr) : 0.f; \
    float w6 = (S##a1.z > 0) ? __builtin_amdgcn_exp2f(leaky_max(sr + S##t1.z, ALPHA) - cr) : 0.f; \
    float w7 = (S##a1.w > 0) ? __builtin_amdgcn_exp2f(leaky_max(sr + S##t1.w, ALPHA) - cr) : 0.f; \
    lsum += ((w0 + w1) + (w2 + w3)) + ((w4 + w5) + (w6 + w7));                 \
    union { short8 s; unsigned u[4]; } afu_;                                    \
    afu_.u[0] = cvt_pk_bf16(w0, w1);                                            \
    afu_.u[1] = cvt_pk_bf16(w2, w3);                                            \
    afu_.u[2] = cvt_pk_bf16(w4, w5);                                            \
    afu_.u[3] = cvt_pk_bf16(w6, w7);                                            \
    const short8 af_ = afu_.s;                                                  \
    acc0 = __builtin_amdgcn_mfma_f32_16x16x32_bf16(af_, S##v0, acc0, 0, 0, 0);  \
    acc1 = __builtin_amdgcn_mfma_f32_16x16x32_bf16(af_, S##v1, acc1, 0, 0, 0);  \
    acc2 = __builtin_amdgcn_mfma_f32_16x16x32_bf16(af_, S##v2, acc2, 0, 0, 0);  \
    acc3 = __builtin_amdgcn_mfma_f32_16x16x32_bf16(af_, S##v3, acc3, 0, 0, 0);  \
  } while (0)

  ISSUE(A, 0);
  __builtin_amdgcn_sched_barrier(0);
#pragma unroll 1
  for (int c = 0; c < NC - 2; c += 2) {
    ISSUE(B, c + 1);
    __builtin_amdgcn_sched_barrier(0);
    COMPUTE(A);
    ISSUE(A, c + 2);
    __builtin_amdgcn_sched_barrier(0);
    COMPUTE(B);
  }
  ISSUE(B, NC - 1);
  __builtin_amdgcn_sched_barrier(0);
  COMPUTE(A);
  COMPUTE(B);
#undef ISSUE
#undef COMPUTE

  // denominator partial: reduce lsum over the 4 quads holding the same row m
  float v = lsum;
  v += __shfl_down(v, 32);
  v += __shfl_down(v, 16);
  if (lane < 16) lpart[(size_t)js * BB * NT + (size_t)b * NT + i0 + wv * 16 + m] = v;

  // numerator partial: D layout col=lane&15, row=(lane>>4)*4+reg
  float* op = outpart + (size_t)js * BB * NT * FO +
              ((size_t)(b * NT) + i0 + wv * 16 + q * 4) * FO + m;
#pragma unroll
  for (int reg = 0; reg < 4; ++reg) {
    op[(size_t)reg * FO + 0 * 16] = acc0[reg];
    op[(size_t)reg * FO + 1 * 16] = acc1[reg];
    op[(size_t)reg * FO + 2 * 16] = acc2[reg];
    op[(size_t)reg * FO + 3 * 16] = acc3[reg];
  }
}

// out[i,f] = leaky( (sum_js outpart) / (sum_js lpart), 0.01 ), float4-vectorized
template <int JS>
__global__ __launch_bounds__(256) void k_fin(const float* __restrict__ outpart,
                                             const float* __restrict__ lpart,
                                             float* __restrict__ out) {
  const size_t NP = (size_t)BB * NT * FO;
  const int idx = blockIdx.x * 256 + threadIdx.x;
  const int row = idx >> 4;
  float l = 0.f;
#pragma unroll
  for (int s = 0; s < JS; ++s) l += lpart[(size_t)s * BB * NT + row];
  const float inv = 1.f / l;
  float4 acc = {0.f, 0.f, 0.f, 0.f};
#pragma unroll
  for (int s = 0; s < JS; ++s) {
    float4 v = ((const float4*)(outpart + (size_t)s * NP))[idx];
    acc.x += v.x; acc.y += v.y; acc.z += v.z; acc.w += v.w;
  }
  float4 o;
  o.x = leaky_max(acc.x * inv, OUT_SLOPE);
  o.y = leaky_max(acc.y * inv, OUT_SLOPE);
  o.z = leaky_max(acc.z * inv, OUT_SLOPE);
  o.w = leaky_max(acc.w * inv, OUT_SLOPE);
  ((float4*)out)[idx] = o;
}

extern "C" void kernel_launch(void* const* d_in, const int* in_sizes, int n_in,
                              void* d_out, int out_size, void* d_ws, size_t ws_size,
                              hipStream_t stream) {
  const float* h   = (const float*)d_in[0];  // [B, Nt, Ft]
  const float* ctx = (const float*)d_in[1];  // [B, Ns, Fs]
  const int*   adj = (const int*)d_in[2];    // [B, Nt, Ns]
  const float* Ws  = (const float*)d_in[3];  // [Fs, Fo]
  const float* Wt  = (const float*)d_in[4];  // [Ft, Fo]
  const float* a   = (const float*)d_in[5];  // [2*Fo, 1]
  float* out = (float*)d_out;                // [B, Nt, Fo] fp32
  float* ws = (float*)d_ws;

  // workspace layout (floats); JSPLIT=4 (~19.3 MB), every element written before read
  float* outpart = ws;                                        // JSPLIT * B*NT*FO
  float* lpart   = outpart + (size_t)JSPLIT * BB * NT * FO;   // JSPLIT * B*NT
  float* tvec    = lpart + (size_t)JSPLIT * BB * NT;          // 16384
  float* svec    = tvec + BB * NS;                            // 16384
  float* wa      = svec + BB * NS;                            // 256
  float* tmax    = wa + 256;                                  // 4
  short* vT      = (short*)(tmax + 4);                        // B*FO*NS bf16 = 2 MB

  k_wa<<<1, 256, 0, stream>>>(Wt, a, wa);
  k_t<<<(BB * NT) / 4, 256, 0, stream>>>(h, wa, tvec);
  k_tmax<<<BB, 256, 0, stream>>>(tvec, tmax);
  k_wsctx<<<(BB * NS) / 16, 256, 0, stream>>>(ctx, Ws, a, vT, svec);
  k_part<JSPLIT><<<(BB * NT / 64) * JSPLIT, 256, 0, stream>>>(adj, vT, svec, tvec,
                                                              tmax, outpart, lpart);
  k_fin<JSPLIT><<<(BB * NT * FO / 4) / 256, 256, 0, stream>>>(outpart, lpart, out);
}

// Round 7
// 491.603 us; speedup vs baseline: 1.0398x; 1.0034x over previous
//
#include <hip/hip_runtime.h>

// Problem constants (fixed by the reference)
#define BB 4
#define NS 4096
#define NT 4096
#define FS 256
#define FT 256
#define FO 64
#define ALPHA 0.2f
#define OUT_SLOPE 0.01f
#define JSPLIT 4
#define L2E 1.4426950408889634f  // log2(e): score vectors pre-scaled so k_part uses exp2

typedef __attribute__((ext_vector_type(8))) short short8;
typedef __attribute__((ext_vector_type(4))) float floatx4;

__device__ __forceinline__ float leaky_max(float x, float s) { return fmaxf(x, s * x); }

// fp32 -> bf16 round-to-nearest-even (scalar path, k_wsctx)
__device__ __forceinline__ short f2bf(float x) {
  union { float f; unsigned u; } c; c.f = x;
  unsigned r = c.u + 0x7fffu + ((c.u >> 16) & 1u);
  return (short)(r >> 16);
}

// packed fp32x2 -> bf16x2 (gfx950; lo -> bits[15:0])
__device__ __forceinline__ unsigned cvt_pk_bf16(float lo, float hi) {
  unsigned r;
  asm("v_cvt_pk_bf16_f32 %0, %1, %2" : "=v"(r) : "v"(lo), "v"(hi));
  return r;
}

// wa[f] = L2E * sum_o Wt[f, o] * a[FO + o]
__global__ void k_wa(const float* __restrict__ Wt, const float* __restrict__ a,
                     float* __restrict__ wa) {
  int f = threadIdx.x;
  float acc = 0.f;
#pragma unroll
  for (int o = 0; o < FO; ++o) acc += Wt[f * FO + o] * a[FO + o];
  wa[f] = acc * L2E;
}

// t[row] = dot(h[row, :256], wa)   one wave per row (log2e-scaled via wa)
__global__ __launch_bounds__(256) void k_t(const float* __restrict__ h,
                                           const float* __restrict__ wa,
                                           float* __restrict__ tvec) {
  int lane = threadIdx.x & 63, wave = threadIdx.x >> 6;
  int row = blockIdx.x * 4 + wave;
  const float4* hp = (const float4*)(h + (size_t)row * FT);
  const float4* wp = (const float4*)wa;
  float4 hv = hp[lane], wv = wp[lane];
  float acc = hv.x * wv.x + hv.y * wv.y + hv.z * wv.z + hv.w * wv.w;
#pragma unroll
  for (int off = 32; off; off >>= 1) acc += __shfl_down(acc, off);
  if (lane == 0) tvec[row] = acc;
}

// per-batch max of t (softmax shift)
__global__ __launch_bounds__(256) void k_tmax(const float* __restrict__ tvec,
                                              float* __restrict__ tmax) {
  __shared__ float red[256];
  int b = blockIdx.x, tid = threadIdx.x;
  float m = -3.0e38f;
  for (int j = tid; j < NS; j += 256) m = fmaxf(m, tvec[b * NS + j]);
  red[tid] = m;
  __syncthreads();
  for (int s = 128; s; s >>= 1) {
    if (tid < s) red[tid] = fmaxf(red[tid], red[tid + s]);
    __syncthreads();
  }
  if (tid == 0) tmax[b] = red[0];
}

// Ws_ctx = ctx @ Ws; writes TRANSPOSED bf16 vT[b][f][row] and
// s[row] = L2E * (Ws_ctx[row,:] @ a[:64]).  One wave per 4 rows, 64 lanes = f.
__global__ __launch_bounds__(256) void k_wsctx(const float* __restrict__ ctx,
                                               const float* __restrict__ Ws,
                                               const float* __restrict__ a,
                                               short* __restrict__ vT,
                                               float* __restrict__ svec) {
  const int f = threadIdx.x & 63, wave = threadIdx.x >> 6;
  const int row0 = blockIdx.x * 16 + wave * 4;
  const float4* c0 = (const float4*)(ctx + (size_t)(row0 + 0) * FS);
  const float4* c1 = (const float4*)(ctx + (size_t)(row0 + 1) * FS);
  const float4* c2 = (const float4*)(ctx + (size_t)(row0 + 2) * FS);
  const float4* c3 = (const float4*)(ctx + (size_t)(row0 + 3) * FS);
  float r0 = 0.f, r1 = 0.f, r2 = 0.f, r3 = 0.f;
#pragma unroll 2
  for (int k4 = 0; k4 < FS / 4; ++k4) {
    const float w0 = Ws[(k4 * 4 + 0) * FO + f];
    const float w1 = Ws[(k4 * 4 + 1) * FO + f];
    const float w2 = Ws[(k4 * 4 + 2) * FO + f];
    const float w3 = Ws[(k4 * 4 + 3) * FO + f];
    float4 x;
    x = c0[k4]; r0 += x.x * w0 + x.y * w1 + x.z * w2 + x.w * w3;
    x = c1[k4]; r1 += x.x * w0 + x.y * w1 + x.z * w2 + x.w * w3;
    x = c2[k4]; r2 += x.x * w0 + x.y * w1 + x.z * w2 + x.w * w3;
    x = c3[k4]; r3 += x.x * w0 + x.y * w1 + x.z * w2 + x.w * w3;
  }
  const int b = row0 >> 12;
  const int rloc = row0 & (NS - 1);
  short* vp = vT + ((size_t)b * FO + f) * NS + rloc;
  vp[0] = f2bf(r0); vp[1] = f2bf(r1); vp[2] = f2bf(r2); vp[3] = f2bf(r3);

  const float af = a[f] * L2E;
  float s0 = r0 * af, s1 = r1 * af, s2 = r2 * af, s3 = r3 * af;
#pragma unroll
  for (int off = 32; off; off >>= 1) {
    s0 += __shfl_down(s0, off);
    s1 += __shfl_down(s1, off);
    s2 += __shfl_down(s2, off);
    s3 += __shfl_down(s3, off);
  }
  if (f == 0) {
    svec[row0 + 0] = s0;
    svec[row0 + 1] = s1;
    svec[row0 + 2] = s2;
    svec[row0 + 3] = s3;
  }
}

// MFMA partial attention, explicitly software-pipelined (depth-1 full-chunk
// double-buffer).  The previous version compiled to VGPR=40: the compiler
// recycled one load-register set per chunk, draining vmcnt inside every
// chunk -> ~1400 cy serial/chunk, all pipes <13% busy.  Here two named
// register sets alternate; chunk c+1's 8 loads are issued before chunk c's
// compute, so one full chunk (8x16B x 64 lanes) stays in flight per wave.
// __launch_bounds__(256,4) lifts the VGPR cap to 128 (~112 used).
template <int JS>
__global__ __launch_bounds__(256, 4) void k_part(const int* __restrict__ adj,
                                                 const short* __restrict__ vT,
                                                 const float* __restrict__ svec,
                                                 const float* __restrict__ tvec,
                                                 const float* __restrict__ tmax,
                                                 float* __restrict__ outpart,
                                                 float* __restrict__ lpart) {
  const int lane = threadIdx.x & 63;
  const int wv = threadIdx.x >> 6;   // 0..3
  const int m = lane & 15;           // A row within 16 / B,D col (f within 16)
  const int q = lane >> 4;           // quad: k-offset q*8

  constexpr int LOG = (JS == 8) ? 3 : 2;
  constexpr int NC = (NS / JS) / 32;     // 32-j chunks per block
  const int tile = blockIdx.x >> LOG;
  const int js = blockIdx.x & (JS - 1);
  const int b = tile >> 6;
  const int i0 = (tile & 63) * 64;
  const int jbase = js * (NS / JS);

  const int r = i0 + wv * 16 + m;
  const float sr = svec[b * NS + r];
  const float cr = leaky_max(sr + tmax[b], ALPHA);

  const int* arow = adj + ((size_t)(b * NT) + r) * NS + jbase;
  const float* tp = tvec + b * NS + jbase;
  const short* vp0 = vT + ((size_t)b * FO + m) * NS + jbase;

  floatx4 acc0 = {0.f, 0.f, 0.f, 0.f};
  floatx4 acc1 = {0.f, 0.f, 0.f, 0.f};
  floatx4 acc2 = {0.f, 0.f, 0.f, 0.f};
  floatx4 acc3 = {0.f, 0.f, 0.f, 0.f};
  float lsum = 0.f;

  // two named full-chunk register sets
  int4 Aa0, Aa1; float4 At0, At1; short8 Av0, Av1, Av2, Av3;
  int4 Ba0, Ba1; float4 Bt0, Bt1; short8 Bv0, Bv1, Bv2, Bv3;

#define ISSUE(S, jc) do {                                        \
    const int j0_ = (jc) * 32 + q * 8;                           \
    S##a0 = *(const int4*)(arow + j0_);                          \
    S##a1 = *(const int4*)(arow + j0_ + 4);                      \
    S##t0 = *(const float4*)(tp + j0_);                          \
    S##t1 = *(const float4*)(tp + j0_ + 4);                      \
    S##v0 = *(const short8*)(vp0 + 0 * 16 * NS + j0_);           \
    S##v1 = *(const short8*)(vp0 + 1 * 16 * NS + j0_);           \
    S##v2 = *(const short8*)(vp0 + 2 * 16 * NS + j0_);           \
    S##v3 = *(const short8*)(vp0 + 3 * 16 * NS + j0_);           \
  } while (0)

#define COMPUTE(S) do {                                                         \
    float w0 = (S##a0.x > 0) ? __builtin_amdgcn_exp2f(leaky_max(sr + S##t0.x, ALPHA) - cr) : 0.f; \
    float w1 = (S##a0.y > 0) ? __builtin_amdgcn_exp2f(leaky_max(sr + S##t0.y, ALPHA) - cr) : 0.f; \
    float w2 = (S##a0.z > 0) ? __builtin_amdgcn_exp2f(leaky_max(sr + S##t0.z, ALPHA) - cr) : 0.f; \
    float w3 = (S##a0.w > 0) ? __builtin_amdgcn_exp2f(leaky_max(sr + S##t0.w, ALPHA) - cr) : 0.f; \
    float w4 = (S##a1.x > 0) ? __builtin_amdgcn_exp2f(leaky_max(sr + S##t1.x, ALPHA) - cr) : 0.f; \
    float w5 = (S##a1.y > 0) ? __builtin_amdgcn_exp2f(leaky_max(sr + S##t1.y, ALPHA) - cr) : 0.f; \
    float w6 = (S##a1.z > 0) ? __builtin_amdgcn_exp2f(leaky_max(sr + S##t1.z, ALPHA) - cr) : 0.f; \
    float w7 = (S##a1.w > 0) ? __builtin_amdgcn_exp2f(leaky_max(sr + S##t1.w, ALPHA) - cr) : 0.f; \
    lsum += ((w0 + w1) + (w2 + w3)) + ((w4 + w5) + (w6 + w7));                 \
    union { short8 s; unsigned u[4]; } afu_;                                    \
    afu_.u[0] = cvt_pk_bf16(w0, w1);                                            \
    afu_.u[1] = cvt_pk_bf16(w2, w3);                                            \
    afu_.u[2] = cvt_pk_bf16(w4, w5);                                            \
    afu_.u[3] = cvt_pk_bf16(w6, w7);                                            \
    const short8 af_ = afu_.s;                                                  \
    acc0 = __builtin_amdgcn_mfma_f32_16x16x32_bf16(af_, S##v0, acc0, 0, 0, 0);  \
    acc1 = __builtin_amdgcn_mfma_f32_16x16x32_bf16(af_, S##v1, acc1, 0, 0, 0);  \
    acc2 = __builtin_amdgcn_mfma_f32_16x16x32_bf16(af_, S##v2, acc2, 0, 0, 0);  \
    acc3 = __builtin_amdgcn_mfma_f32_16x16x32_bf16(af_, S##v3, acc3, 0, 0, 0);  \
  } while (0)

  ISSUE(A, 0);
  __builtin_amdgcn_sched_barrier(0);
#pragma unroll 1
  for (int c = 0; c < NC - 2; c += 2) {
    ISSUE(B, c + 1);
    __builtin_amdgcn_sched_barrier(0);
    COMPUTE(A);
    ISSUE(A, c + 2);
    __builtin_amdgcn_sched_barrier(0);
    COMPUTE(B);
  }
  ISSUE(B, NC - 1);
  __builtin_amdgcn_sched_barrier(0);
  COMPUTE(A);
  COMPUTE(B);
#undef ISSUE
#undef COMPUTE

  // denominator partial: reduce lsum over the 4 quads holding the same row m
  float v = lsum;
  v += __shfl_down(v, 32);
  v += __shfl_down(v, 16);
  if (lane < 16) lpart[(size_t)js * BB * NT + (size_t)b * NT + i0 + wv * 16 + m] = v;

  // numerator partial: D layout col=lane&15, row=(lane>>4)*4+reg
  float* op = outpart + (size_t)js * BB * NT * FO +
              ((size_t)(b * NT) + i0 + wv * 16 + q * 4) * FO + m;
#pragma unroll
  for (int reg = 0; reg < 4; ++reg) {
    op[(size_t)reg * FO + 0 * 16] = acc0[reg];
    op[(size_t)reg * FO + 1 * 16] = acc1[reg];
    op[(size_t)reg * FO + 2 * 16] = acc2[reg];
    op[(size_t)reg * FO + 3 * 16] = acc3[reg];
  }
}

// out[i,f] = leaky( (sum_js outpart) / (sum_js lpart), 0.01 ), float4-vectorized
template <int JS>
__global__ __launch_bounds__(256) void k_fin(const float* __restrict__ outpart,
                                             const float* __restrict__ lpart,
                                             float* __restrict__ out) {
  const size_t NP = (size_t)BB * NT * FO;
  const int idx = blockIdx.x * 256 + threadIdx.x;
  const int row = idx >> 4;
  float l = 0.f;
#pragma unroll
  for (int s = 0; s < JS; ++s) l += lpart[(size_t)s * BB * NT + row];
  const float inv = 1.f / l;
  float4 acc = {0.f, 0.f, 0.f, 0.f};
#pragma unroll
  for (int s = 0; s < JS; ++s) {
    float4 v = ((const float4*)(outpart + (size_t)s * NP))[idx];
    acc.x += v.x; acc.y += v.y; acc.z += v.z; acc.w += v.w;
  }
  float4 o;
  o.x = leaky_max(acc.x * inv, OUT_SLOPE);
  o.y = leaky_max(acc.y * inv, OUT_SLOPE);
  o.z = leaky_max(acc.z * inv, OUT_SLOPE);
  o.w = leaky_max(acc.w * inv, OUT_SLOPE);
  ((float4*)out)[idx] = o;
}

extern "C" void kernel_launch(void* const* d_in, const int* in_sizes, int n_in,
                              void* d_out, int out_size, void* d_ws, size_t ws_size,
                              hipStream_t stream) {
  const float* h   = (const float*)d_in[0];  // [B, Nt, Ft]
  const float* ctx = (const float*)d_in[1];  // [B, Ns, Fs]
  const int*   adj = (const int*)d_in[2];    // [B, Nt, Ns]
  const float* Ws  = (const float*)d_in[3];  // [Fs, Fo]
  const float* Wt  = (const float*)d_in[4];  // [Ft, Fo]
  const float* a   = (const float*)d_in[5];  // [2*Fo, 1]
  float* out = (float*)d_out;                // [B, Nt, Fo] fp32
  float* ws = (float*)d_ws;

  // workspace layout (floats); JSPLIT=4 (~19.3 MB), every element written before read
  float* outpart = ws;                                        // JSPLIT * B*NT*FO
  float* lpart   = outpart + (size_t)JSPLIT * BB * NT * FO;   // JSPLIT * B*NT
  float* tvec    = lpart + (size_t)JSPLIT * BB * NT;          // 16384
  float* svec    = tvec + BB * NS;                            // 16384
  float* wa      = svec + BB * NS;                            // 256
  float* tmax    = wa + 256;                                  // 4
  short* vT      = (short*)(tmax + 4);                        // B*FO*NS bf16 = 2 MB

  k_wa<<<1, 256, 0, stream>>>(Wt, a, wa);
  k_t<<<(BB * NT) / 4, 256, 0, stream>>>(h, wa, tvec);
  k_tmax<<<BB, 256, 0, stream>>>(tvec, tmax);
  k_wsctx<<<(BB * NS) / 16, 256, 0, stream>>>(ctx, Ws, a, vT, svec);
  k_part<JSPLIT><<<(BB * NT / 64) * JSPLIT, 256, 0, stream>>>(adj, vT, svec, tvec,
                                                              tmax, outpart, lpart);
  k_fin<JSPLIT><<<(BB * NT * FO / 4) / 256, 256, 0, stream>>>(outpart, lpart, out);
}

// Round 9
// 460.526 us; speedup vs baseline: 1.1100x; 1.0675x over previous
//
#include <hip/hip_runtime.h>

// Problem constants (fixed by the reference)
#define BB 4
#define NS 4096
#define NT 4096
#define FS 256
#define FT 256
#define FO 64
#define ALPHA 0.2f
#define OUT_SLOPE 0.01f
#define JSPLIT 4
#define L2E 1.4426950408889634f  // log2(e): score vectors pre-scaled so k_part uses exp2

typedef __attribute__((ext_vector_type(8))) short short8;
typedef __attribute__((ext_vector_type(4))) float floatx4;

__device__ __forceinline__ float leaky_max(float x, float s) { return fmaxf(x, s * x); }

// fp32 -> bf16 round-to-nearest-even (scalar path, k_wsctx)
__device__ __forceinline__ short f2bf(float x) {
  union { float f; unsigned u; } c; c.f = x;
  unsigned r = c.u + 0x7fffu + ((c.u >> 16) & 1u);
  return (short)(r >> 16);
}

// packed fp32x2 -> bf16x2 (gfx950; lo -> bits[15:0])
__device__ __forceinline__ unsigned cvt_pk_bf16(float lo, float hi) {
  unsigned r;
  asm("v_cvt_pk_bf16_f32 %0, %1, %2" : "=v"(r) : "v"(lo), "v"(hi));
  return r;
}

// wa[f] = L2E * sum_o Wt[f, o] * a[FO + o]
__global__ void k_wa(const float* __restrict__ Wt, const float* __restrict__ a,
                     float* __restrict__ wa) {
  int f = threadIdx.x;
  float acc = 0.f;
#pragma unroll
  for (int o = 0; o < FO; ++o) acc += Wt[f * FO + o] * a[FO + o];
  wa[f] = acc * L2E;
}

// t[row] = dot(h[row, :256], wa)   one wave per row (log2e-scaled via wa)
__global__ __launch_bounds__(256) void k_t(const float* __restrict__ h,
                                           const float* __restrict__ wa,
                                           float* __restrict__ tvec) {
  int lane = threadIdx.x & 63, wave = threadIdx.x >> 6;
  int row = blockIdx.x * 4 + wave;
  const float4* hp = (const float4*)(h + (size_t)row * FT);
  const float4* wp = (const float4*)wa;
  float4 hv = hp[lane], wv = wp[lane];
  float acc = hv.x * wv.x + hv.y * wv.y + hv.z * wv.z + hv.w * wv.w;
#pragma unroll
  for (int off = 32; off; off >>= 1) acc += __shfl_down(acc, off);
  if (lane == 0) tvec[row] = acc;
}

// per-batch max of t (softmax shift)
__global__ __launch_bounds__(256) void k_tmax(const float* __restrict__ tvec,
                                              float* __restrict__ tmax) {
  __shared__ float red[256];
  int b = blockIdx.x, tid = threadIdx.x;
  float m = -3.0e38f;
  for (int j = tid; j < NS; j += 256) m = fmaxf(m, tvec[b * NS + j]);
  red[tid] = m;
  __syncthreads();
  for (int s = 128; s; s >>= 1) {
    if (tid < s) red[tid] = fmaxf(red[tid], red[tid + s]);
    __syncthreads();
  }
  if (tid == 0) tmax[b] = red[0];
}

// Ws_ctx = ctx @ Ws; writes bf16 vT TILED as [b][jblk=row/32][f][jin=row%32]
// (so k_part's B-fragment loads are CONTIGUOUS 1KB per instruction instead of
// 16 scattered 8KB-strided lines), and s[row] = L2E * (Ws_ctx[row,:]@a[:64]).
// One wave per 4 rows, 64 lanes = f.  Per-lane MFMA fragment VALUES are
// identical to the verified flat-[f][row] layout -- only addresses moved.
__global__ __launch_bounds__(256) void k_wsctx(const float* __restrict__ ctx,
                                               const float* __restrict__ Ws,
                                               const float* __restrict__ a,
                                               short* __restrict__ vT,
                                               float* __restrict__ svec) {
  const int f = threadIdx.x & 63, wave = threadIdx.x >> 6;
  const int row0 = blockIdx.x * 16 + wave * 4;
  const float4* c0 = (const float4*)(ctx + (size_t)(row0 + 0) * FS);
  const float4* c1 = (const float4*)(ctx + (size_t)(row0 + 1) * FS);
  const float4* c2 = (const float4*)(ctx + (size_t)(row0 + 2) * FS);
  const float4* c3 = (const float4*)(ctx + (size_t)(row0 + 3) * FS);
  float r0 = 0.f, r1 = 0.f, r2 = 0.f, r3 = 0.f;
#pragma unroll 2
  for (int k4 = 0; k4 < FS / 4; ++k4) {
    const float w0 = Ws[(k4 * 4 + 0) * FO + f];
    const float w1 = Ws[(k4 * 4 + 1) * FO + f];
    const float w2 = Ws[(k4 * 4 + 2) * FO + f];
    const float w3 = Ws[(k4 * 4 + 3) * FO + f];
    float4 x;
    x = c0[k4]; r0 += x.x * w0 + x.y * w1 + x.z * w2 + x.w * w3;
    x = c1[k4]; r1 += x.x * w0 + x.y * w1 + x.z * w2 + x.w * w3;
    x = c2[k4]; r2 += x.x * w0 + x.y * w1 + x.z * w2 + x.w * w3;
    x = c3[k4]; r3 += x.x * w0 + x.y * w1 + x.z * w2 + x.w * w3;
  }
  const int b = row0 >> 12;             // NS = 4096 rows per batch
  const int rloc = row0 & (NS - 1);
  // tiled write: [b][rloc>>5][f][rloc&31]; 4 consecutive rows stay in one tile
  short* vp = vT + (((size_t)b * (NS / 32) + (rloc >> 5)) * FO + f) * 32 + (rloc & 31);
  vp[0] = f2bf(r0); vp[1] = f2bf(r1); vp[2] = f2bf(r2); vp[3] = f2bf(r3);

  const float af = a[f] * L2E;
  float s0 = r0 * af, s1 = r1 * af, s2 = r2 * af, s3 = r3 * af;
#pragma unroll
  for (int off = 32; off; off >>= 1) {
    s0 += __shfl_down(s0, off);
    s1 += __shfl_down(s1, off);
    s2 += __shfl_down(s2, off);
    s3 += __shfl_down(s3, off);
  }
  if (f == 0) {
    svec[row0 + 0] = s0;
    svec[row0 + 1] = s1;
    svec[row0 + 2] = s2;
    svec[row0 + 3] = s3;
  }
}

// MFMA partial attention, depth-1 double-buffered -- structure byte-identical
// to the twice-verified 491us version.  ONLY the vT addressing changed to the
// tiled layout: per chunk the 4 B-fragment loads are each 64 lanes x 16B
// CONTIGUOUS (8 full 128B txns, L2-shared across the block's 4 waves) vs 16
// scattered half-used lines before.  Theory: k_part is VMEM-transaction-rate
// bound (~1.25 txn/cy/CU vs ~1/cy pipe); this cuts ~100 -> ~44 txn/chunk.
template <int JS>
__global__ __launch_bounds__(256, 4) void k_part(const int* __restrict__ adj,
                                                 const short* __restrict__ vT,
                                                 const float* __restrict__ svec,
                                                 const float* __restrict__ tvec,
                                                 const float* __restrict__ tmax,
                                                 float* __restrict__ outpart,
                                                 float* __restrict__ lpart) {
  const int lane = threadIdx.x & 63;
  const int wv = threadIdx.x >> 6;   // 0..3
  const int m = lane & 15;           // A row within 16 / B,D col (f within 16)
  const int q = lane >> 4;           // quad: k-offset q*8

  constexpr int LOG = (JS == 8) ? 3 : 2;
  constexpr int NC = (NS / JS) / 32;     // 32-j chunks per block
  const int tile = blockIdx.x >> LOG;
  const int js = blockIdx.x & (JS - 1);
  const int b = tile >> 6;
  const int i0 = (tile & 63) * 64;
  const int jbase = js * (NS / JS);

  const int r = i0 + wv * 16 + m;
  const float sr = svec[b * NS + r];
  const float cr = leaky_max(sr + tmax[b], ALPHA);

  const int* arow = adj + ((size_t)(b * NT) + r) * NS + jbase;
  const float* tp = tvec + b * NS + jbase;
  // tiled vT base for this block's j-window: tiles (jbase/32 + jc), jc=0..NC-1
  // per-tile: 64 f-rows x 32 j shorts = 2048 shorts; this lane reads f-row
  // (fb*16 + m), j = q*8..q*8+7  ->  contiguous across the 64 lanes.
  const short* vp0 = vT + ((size_t)b * (NS / 32) + (jbase >> 5)) * (FO * 32) +
                     m * 32 + q * 8;

  floatx4 acc0 = {0.f, 0.f, 0.f, 0.f};
  floatx4 acc1 = {0.f, 0.f, 0.f, 0.f};
  floatx4 acc2 = {0.f, 0.f, 0.f, 0.f};
  floatx4 acc3 = {0.f, 0.f, 0.f, 0.f};
  float lsum = 0.f;

  // two named full-chunk register sets
  int4 Aa0, Aa1; float4 At0, At1; short8 Av0, Av1, Av2, Av3;
  int4 Ba0, Ba1; float4 Bt0, Bt1; short8 Bv0, Bv1, Bv2, Bv3;

#define ISSUE(S, jc) do {                                        \
    const int j0_ = (jc) * 32 + q * 8;                           \
    const short* vb_ = vp0 + (size_t)(jc) * (FO * 32);           \
    S##a0 = *(const int4*)(arow + j0_);                          \
    S##a1 = *(const int4*)(arow + j0_ + 4);                      \
    S##t0 = *(const float4*)(tp + j0_);                          \
    S##t1 = *(const float4*)(tp + j0_ + 4);                      \
    S##v0 = *(const short8*)(vb_ + 0 * 16 * 32);                 \
    S##v1 = *(const short8*)(vb_ + 1 * 16 * 32);                 \
    S##v2 = *(const short8*)(vb_ + 2 * 16 * 32);                 \
    S##v3 = *(const short8*)(vb_ + 3 * 16 * 32);                 \
  } while (0)

#define COMPUTE(S) do {                                                         \
    float w0 = (S##a0.x > 0) ? __builtin_amdgcn_exp2f(leaky_max(sr + S##t0.x, ALPHA) - cr) : 0.f; \
    float w1 = (S##a0.y > 0) ? __builtin_amdgcn_exp2f(leaky_max(sr + S##t0.y, ALPHA) - cr) : 0.f; \
    float w2 = (S##a0.z > 0) ? __builtin_amdgcn_exp2f(leaky_max(sr + S##t0.z, ALPHA) - cr) : 0.f; \
    float w3 = (S##a0.w > 0) ? __builtin_amdgcn_exp2f(leaky_max(sr + S##t0.w, ALPHA) - cr) : 0.f; \
    float w4 = (S##a1.x > 0) ? __builtin_amdgcn_exp2f(leaky_max(sr + S##t1.x, ALPHA) - cr) : 0.f; \
    float w5 = (S##a1.y > 0) ? __builtin_amdgcn_exp2f(leaky_max(sr + S##t1.y, ALPHA) - cr) : 0.f; \
    float w6 = (S##a1.z > 0) ? __builtin_amdgcn_exp2f(leaky_max(sr + S##t1.z, ALPHA) - cr) : 0.f; \
    float w7 = (S##a1.w > 0) ? __builtin_amdgcn_exp2f(leaky_max(sr + S##t1.w, ALPHA) - cr) : 0.f; \
    lsum += ((w0 + w1) + (w2 + w3)) + ((w4 + w5) + (w6 + w7));                 \
    union { short8 s; unsigned u[4]; } afu_;                                    \
    afu_.u[0] = cvt_pk_bf16(w0, w1);                                            \
    afu_.u[1] = cvt_pk_bf16(w2, w3);                                            \
    afu_.u[2] = cvt_pk_bf16(w4, w5);                                            \
    afu_.u[3] = cvt_pk_bf16(w6, w7);                                            \
    const short8 af_ = afu_.s;                                                  \
    acc0 = __builtin_amdgcn_mfma_f32_16x16x32_bf16(af_, S##v0, acc0, 0, 0, 0);  \
    acc1 = __builtin_amdgcn_mfma_f32_16x16x32_bf16(af_, S##v1, acc1, 0, 0, 0);  \
    acc2 = __builtin_amdgcn_mfma_f32_16x16x32_bf16(af_, S##v2, acc2, 0, 0, 0);  \
    acc3 = __builtin_amdgcn_mfma_f32_16x16x32_bf16(af_, S##v3, acc3, 0, 0, 0);  \
  } while (0)

  ISSUE(A, 0);
  __builtin_amdgcn_sched_barrier(0);
#pragma unroll 1
  for (int c = 0; c < NC - 2; c += 2) {
    ISSUE(B, c + 1);
    __builtin_amdgcn_sched_barrier(0);
    COMPUTE(A);
    ISSUE(A, c + 2);
    __builtin_amdgcn_sched_barrier(0);
    COMPUTE(B);
  }
  ISSUE(B, NC - 1);
  __builtin_amdgcn_sched_barrier(0);
  COMPUTE(A);
  COMPUTE(B);
#undef ISSUE
#undef COMPUTE

  // denominator partial: reduce lsum over the 4 quads holding the same row m
  float v = lsum;
  v += __shfl_down(v, 32);
  v += __shfl_down(v, 16);
  if (lane < 16) lpart[(size_t)js * BB * NT + (size_t)b * NT + i0 + wv * 16 + m] = v;

  // numerator partial: D layout col=lane&15, row=(lane>>4)*4+reg
  float* op = outpart + (size_t)js * BB * NT * FO +
              ((size_t)(b * NT) + i0 + wv * 16 + q * 4) * FO + m;
#pragma unroll
  for (int reg = 0; reg < 4; ++reg) {
    op[(size_t)reg * FO + 0 * 16] = acc0[reg];
    op[(size_t)reg * FO + 1 * 16] = acc1[reg];
    op[(size_t)reg * FO + 2 * 16] = acc2[reg];
    op[(size_t)reg * FO + 3 * 16] = acc3[reg];
  }
}

// out[i,f] = leaky( (sum_js outpart) / (sum_js lpart), 0.01 ), float4-vectorized
template <int JS>
__global__ __launch_bounds__(256) void k_fin(const float* __restrict__ outpart,
                                             const float* __restrict__ lpart,
                                             float* __restrict__ out) {
  const size_t NP = (size_t)BB * NT * FO;
  const int idx = blockIdx.x * 256 + threadIdx.x;
  const int row = idx >> 4;
  float l = 0.f;
#pragma unroll
  for (int s = 0; s < JS; ++s) l += lpart[(size_t)s * BB * NT + row];
  const float inv = 1.f / l;
  float4 acc = {0.f, 0.f, 0.f, 0.f};
#pragma unroll
  for (int s = 0; s < JS; ++s) {
    float4 v = ((const float4*)(outpart + (size_t)s * NP))[idx];
    acc.x += v.x; acc.y += v.y; acc.z += v.z; acc.w += v.w;
  }
  float4 o;
  o.x = leaky_max(acc.x * inv, OUT_SLOPE);
  o.y = leaky_max(acc.y * inv, OUT_SLOPE);
  o.z = leaky_max(acc.z * inv, OUT_SLOPE);
  o.w = leaky_max(acc.w * inv, OUT_SLOPE);
  ((float4*)out)[idx] = o;
}

extern "C" void kernel_launch(void* const* d_in, const int* in_sizes, int n_in,
                              void* d_out, int out_size, void* d_ws, size_t ws_size,
                              hipStream_t stream) {
  const float* h   = (const float*)d_in[0];  // [B, Nt, Ft]
  const float* ctx = (const float*)d_in[1];  // [B, Ns, Fs]
  const int*   adj = (const int*)d_in[2];    // [B, Nt, Ns]
  const float* Ws  = (const float*)d_in[3];  // [Fs, Fo]
  const float* Wt  = (const float*)d_in[4];  // [Ft, Fo]
  const float* a   = (const float*)d_in[5];  // [2*Fo, 1]
  float* out = (float*)d_out;                // [B, Nt, Fo] fp32
  float* ws = (float*)d_ws;

  // workspace layout (floats); JSPLIT=4 (~19.3 MB), every element written before read
  float* outpart = ws;                                        // JSPLIT * B*NT*FO
  float* lpart   = outpart + (size_t)JSPLIT * BB * NT * FO;   // JSPLIT * B*NT
  float* tvec    = lpart + (size_t)JSPLIT * BB * NT;          // 16384
  float* svec    = tvec + BB * NS;                            // 16384
  float* wa      = svec + BB * NS;                            // 256
  float* tmax    = wa + 256;                                  // 4
  short* vT      = (short*)(tmax + 4);                        // B*FO*NS bf16 = 2 MB

  k_wa<<<1, 256, 0, stream>>>(Wt, a, wa);
  k_t<<<(BB * NT) / 4, 256, 0, stream>>>(h, wa, tvec);
  k_tmax<<<BB, 256, 0, stream>>>(tvec, tmax);
  k_wsctx<<<(BB * NS) / 16, 256, 0, stream>>>(ctx, Ws, a, vT, svec);
  k_part<JSPLIT><<<(BB * NT / 64) * JSPLIT, 256, 0, stream>>>(adj, vT, svec, tvec,
                                                              tmax, outpart, lpart);
  k_fin<JSPLIT><<<(BB * NT * FO / 4) / 256, 256, 0, stream>>>(outpart, lpart, out);
}